// Round 12
// baseline (437.871 us; speedup 1.0000x reference)
//
#include <hip/hip_runtime.h>

#define BB 16
#define NN 1536
#define FF 128
#define SLOPE 0.2f
#define NS 2048
#define CH2 16
#define NCH2 96         // NN/CH2
#define TI 8
#define NPB (NN/8)      // 192 aggdec blocks per sample (also DECP partials)
#define OG 4            // offs scan groups (inline, last chunk block)
#define OC (NCH2/OG)    // 24 chunks per group

// ---- fused: compaction (layer1) + hybrid bitonic sort + scans + row params ----
__global__ __launch_bounds__(1024) void k_sortpre(
    const int* __restrict__ data,            // non-null => layer 1
    const float* __restrict__ embed, const float* __restrict__ decW,
    const float* __restrict__ aS, const float* __restrict__ aD,
    const float* __restrict__ SJb, long sStride,
    const float* __restrict__ SIr, long siStride,
    int* __restrict__ actG, int* __restrict__ cntG,
    float* __restrict__ hN, float* __restrict__ sN,
    float* __restrict__ keyG, int* __restrict__ pjG,
    float* __restrict__ ROWP, int* __restrict__ ctr)
{
  int b = blockIdx.x, t = threadIdx.x;
  if (b == BB){
    __shared__ float rs[2][2];
    if (t < FF){
      float acc = 0.f;
      for (int k=0;k<FF;++k) acc += embed[(long)NN*FF + k] * decW[k*FF + t];
      hN[t] = acc;
      float ps = acc * aS[t];
      float pd = acc * aD[t];
      #pragma unroll
      for (int o=32;o;o>>=1){ ps += __shfl_down(ps,o); pd += __shfl_down(pd,o); }
      if ((t&63)==0){ rs[0][t>>6]=ps; rs[1][t>>6]=pd; }
    }
    __syncthreads();
    if (t==0){ sN[0]=rs[0][0]+rs[0][1]; sN[1]=rs[1][0]+rs[1][1]; }
    return;
  }
  if (t==0) ctr[b] = 0;   // reset completion counter for this layer's k_chunk

  __shared__ float key[NS]; __shared__ int pj[NS];
  __shared__ float sb[NS]; __shared__ float sd[NS];
  __shared__ int cntS;
  int cnt;
  if (data != nullptr){
    __shared__ int s[256];
    const int PER = NN/256;                  // 6
    int local[NN/256]; int nl = 0;
    if (t < 256){
      int base = t*PER;
      #pragma unroll
      for (int u=0; u<PER; ++u){
        if (data[b*NN + base + u] != 0) local[nl++] = base+u;
      }
      s[t]=nl;
    }
    __syncthreads();
    if (t==0){ int run=0; for (int i=0;i<256;i++){ int v=s[i]; s[i]=run; run+=v; }
               cntG[b]=run; cntS=run; }
    __syncthreads();
    if (t < 256){
      int o = s[t];
      for (int u=0; u<nl; ++u) actG[b*NN + o + u] = local[u];
    }
    __syncthreads();
    cnt = cntS;
  } else {
    cnt = cntG[b];
  }

  const float* SJ = SJb + (long)b*sStride;
  const int* act = (data != nullptr) ? actG + b*NN : nullptr;
  int NSort = 32; while (NSort < cnt) NSort <<= 1;    // <= 2048

  for (int e=t; e<NSort; e+=1024){
    if (e<cnt){ int io = act ? act[e] : e; key[e]=SJ[io]; pj[e]=io; }
    else { key[e]=__builtin_inff(); pj[e]=0; }
  }
  __syncthreads();

  // Phase A: k = 2..min(64,NSort) entirely in registers (intra-wave), 0 barriers
  {
    float v0 = (t<NSort)? key[t] : __builtin_inff();
    int   q0 = (t<NSort)? pj[t] : 0;
    float v1 = __builtin_inff(); int q1 = 0;
    bool two = (NSort > 1024);
    if (two){ v1=key[t+1024]; q1=pj[t+1024]; }
    int kmax = (NSort < 64)? NSort : 64;
    for (int k=2; k<=kmax; k<<=1){
      for (int j=k>>1; j>0; j>>=1){
        {
          float ov=__shfl_xor(v0,j); int oq=__shfl_xor(q0,j);
          bool keepmin = (((t & k)==0) == ((t & j)==0));
          bool take = keepmin ? (ov < v0) : (ov > v0);
          if (take){ v0=ov; q0=oq; }
        }
        if (two){
          int e = t+1024;
          float ov=__shfl_xor(v1,j); int oq=__shfl_xor(q1,j);
          bool keepmin = (((e & k)==0) == ((e & j)==0));
          bool take = keepmin ? (ov < v1) : (ov > v1);
          if (take){ v1=ov; q1=oq; }
        }
      }
    }
    if (t < NSort){ key[t]=v0; pj[t]=q0; }
    if (two){ key[t+1024]=v1; pj[t+1024]=q1; }
  }
  __syncthreads();

  // Phase B: k = 128..NSort (LDS for j>=64, shuffles for j<=32)
  for (int k=128; k<=NSort; k<<=1){
    for (int j=k>>1; j>=64; j>>=1){
      for (int e=t; e<NSort; e+=1024){
        int l = e ^ j;
        if (l > e){
          bool asc = ((e & k) == 0);
          float a0=key[e], a1=key[l];
          if (asc ? (a0>a1) : (a0<a1)){
            key[e]=a1; key[l]=a0; int p=pj[e]; pj[e]=pj[l]; pj[l]=p;
          }
        }
      }
      __syncthreads();
    }
    {
      float v0=0.f, v1=0.f; int q0=0, q1=0;
      if (t < NSort){ v0=key[t]; q0=pj[t]; }
      if (NSort > 1024){ v1=key[t+1024]; q1=pj[t+1024]; }
      for (int j=32; j>0; j>>=1){
        {
          float ov=__shfl_xor(v0,j); int oq=__shfl_xor(q0,j);
          bool keepmin = (((t & k)==0) == ((t & j)==0));
          bool take = keepmin ? (ov < v0) : (ov > v0);
          if (take){ v0=ov; q0=oq; }
        }
        if (NSort > 1024){
          int e = t+1024;
          float ov=__shfl_xor(v1,j); int oq=__shfl_xor(q1,j);
          bool keepmin = (((e & k)==0) == ((e & j)==0));
          bool take = keepmin ? (ov < v1) : (ov > v1);
          if (take){ v1=ov; q1=oq; }
        }
      }
      if (t < NSort){ key[t]=v0; pj[t]=q0; }
      if (NSort > 1024){ key[t+1024]=v1; pj[t+1024]=q1; }
    }
    __syncthreads();
  }

  // sb/sd + prefix scan: pair per thread + wave scan + one LDS round
  {
    int e0 = 2*t, e1 = 2*t+1;
    float b0=0.f,b1=0.f,d0=0.f,d1=0.f;
    if (e0 < cnt){ float kk=key[e0]; b0=__expf(kk); d0=__expf(SLOPE*kk); }
    if (e1 < cnt){ float kk=key[e1]; b1=__expf(kk); d1=__expf(SLOPE*kk); }
    float sB=b0+b1, sD=d0+d1;
    int lane = t & 63, wid = t >> 6;
    float iB=sB, iD=sD;
    #pragma unroll
    for (int o=1;o<64;o<<=1){
      float uB=__shfl_up(iB,o), uD=__shfl_up(iD,o);
      if (lane>=o){ iB+=uB; iD+=uD; }
    }
    __shared__ float wsB[16], wsD[16];
    if (lane==63){ wsB[wid]=iB; wsD[wid]=iD; }
    __syncthreads();
    float offB=0.f, offD=0.f;
    for (int w=0; w<wid; ++w){ offB+=wsB[w]; offD+=wsD[w]; }
    float exB = offB + iB - sB;      // exclusive prefix at e0
    float exD = offD + iD - sD;
    if (e0 < NSort){ sb[e0]=exB+b0;    sd[e0]=exD+d0; }
    if (e1 < NSort){ sb[e1]=exB+b0+b1; sd[e1]=exD+d0+d1; }
  }
  __syncthreads();

  // per-row params: boundary search + ai/ci/den, plus keyG/pjG export
  {
    float TBs = sb[(cnt>0)? cnt-1 : 0];
    const float* SIrb = SIr + (data ? 0L : (long)b*siStride);
    for (int r=t; r<cnt; r+=1024){
      float si = data ? SIrb[act[r]] : SIrb[r];
      float th = -si;
      int lo=0, hi=cnt;
      while (lo<hi){ int mid=(lo+hi)>>1; if (key[mid]<=th) lo=mid+1; else hi=mid; }
      float ai=__expf(si), ci=__expf(SLOPE*si);
      float SBv = (lo>0)? sb[lo-1] : 0.f;
      float SDv = (lo>0)? sd[lo-1] : 0.f;
      float4 rp;
      rp.x=ai; rp.y=ci; rp.z = ai*(TBs-SBv)+ci*SDv; rp.w=__int_as_float(lo);
      reinterpret_cast<float4*>(ROWP)[(long)b*NN+r] = rp;
      keyG[(long)b*NN+r]=key[r]; pjG[(long)b*NN+r]=pj[r];
    }
  }
}

// ---- row-matmul (layer 1 only): H = X @ W, SI = H@aSrc, SJ = H@aDst ----
__global__ __launch_bounds__(128) void k_rowmm(const float* __restrict__ Xv,
    const float* __restrict__ W, const float* __restrict__ aS, const float* __restrict__ aD,
    float* __restrict__ H, float* __restrict__ SI, float* __restrict__ SJ)
{
  int r0 = blockIdx.x*8;
  int f = threadIdx.x;
  __shared__ float xs[8][FF];
  #pragma unroll
  for (int r=0;r<8;++r) xs[r][f] = Xv[(long)(r0+r)*FF + f];
  __syncthreads();
  float acc[8]={0.f,0.f,0.f,0.f,0.f,0.f,0.f,0.f};
  for (int k=0;k<FF;k+=4){
    float w0 = W[(k  )*FF + f];
    float w1 = W[(k+1)*FF + f];
    float w2 = W[(k+2)*FF + f];
    float w3 = W[(k+3)*FF + f];
    #pragma unroll
    for (int r=0;r<8;++r){
      float4 x = *reinterpret_cast<const float4*>(&xs[r][k]);
      acc[r] = fmaf(x.x,w0, fmaf(x.y,w1, fmaf(x.z,w2, fmaf(x.w,w3, acc[r]))));
    }
  }
  float as = aS[f], ad = aD[f];
  __shared__ float red[2][8][2];
  #pragma unroll
  for (int r=0;r<8;++r){
    H[(long)(r0+r)*FF + f] = acc[r];
    float ps = acc[r]*as, pd = acc[r]*ad;
    #pragma unroll
    for (int o=32;o;o>>=1){ ps += __shfl_down(ps,o); pd += __shfl_down(pd,o); }
    if ((f&63)==0){ red[0][r][f>>6]=ps; red[1][r][f>>6]=pd; }
  }
  __syncthreads();
  if (f<8){
    SI[r0+f]=red[0][f][0]+red[0][f][1]; SJ[r0+f]=red[1][f][0]+red[1][f][1];
  }
}

// ---- agg stage 2 + inline chunk-offset scan (last-block pattern) ----
// Each block writes its chunk's within-chunk prefixes, then releases via a
// device-scope ACQ_REL atomic on ctr[b]; the 96th block for sample b performs
// the exclusive scan of chunk-end values into OFB/OFD (register-batched, OG
// rounds of OC parallel loads). Replaces the standalone k_offs dispatch.
__global__ __launch_bounds__(128) void k_chunk(
    const float* __restrict__ keyG, const int* __restrict__ pjG,
    const int* __restrict__ cntArr,
    const float* __restrict__ Hb, long hStride,
    float* __restrict__ PP, float* __restrict__ PM,
    float* __restrict__ OFB, float* __restrict__ OFD,
    int* __restrict__ ctr)
{
  int b = blockIdx.y, c = blockIdx.x, f = threadIdx.x;
  int cnt = cntArr[b];
  int k0 = c*CH2;
  if (k0 < cnt){
    int k1 = k0+CH2; if (k1 > cnt) k1 = cnt;
    int kn = k1-k0;
    const float* H = Hb + (long)b*hStride + f;
    __shared__ int pjs[CH2]; __shared__ float wbs[CH2], wds[CH2];
    if (f < CH2 && f < kn){
      float kk = keyG[(long)b*NN + k0 + f];
      pjs[f] = pjG[(long)b*NN + k0 + f];
      wbs[f] = __expf(kk);
      wds[f] = __expf(SLOPE*kk);
    }
    __syncthreads();
    float accB=0.f, accD=0.f;
    float hbuf[8];
    #pragma unroll
    for (int i=0;i<8;i++) hbuf[i] = (i<kn) ? H[(long)pjs[i]*FF] : 0.f;
    long obase = ((long)b*NN + k0)*FF + f;
    int k=0;
    for (; k+8<=kn; k+=8){
      #pragma unroll
      for (int u=0;u<8;u++){
        float hv = hbuf[u];
        int kp = k+u+8;
        hbuf[u] = (kp<kn) ? H[(long)pjs[kp]*FF] : 0.f;
        accB = fmaf(wbs[k+u], hv, accB);
        accD = fmaf(wds[k+u], hv, accD);
        PP[obase + (long)(k+u)*FF] = accB;
        PM[obase + (long)(k+u)*FF] = accD;
      }
    }
    for (; k<kn; ++k){
      float hv = H[(long)pjs[k]*FF];
      accB = fmaf(wbs[k], hv, accB);
      accD = fmaf(wds[k], hv, accD);
      PP[obase + (long)k*FF] = accB;
      PM[obase + (long)k*FF] = accD;
    }
  }
  // completion protocol: release our writes, detect last block of sample b
  __threadfence();
  __shared__ int lastS;
  if (f==0){
    int v = __hip_atomic_fetch_add(&ctr[b], 1, __ATOMIC_ACQ_REL,
                                   __HIP_MEMORY_SCOPE_AGENT);
    lastS = (v == NCH2-1);
  }
  __syncthreads();
  if (!lastS) return;
  __threadfence();
  // inline offs: exclusive scan of chunk-end PP/PM into OFB/OFD
  float rb=0.f, rd=0.f;
  long base = (long)b*(NCH2+1)*FF + f;
  for (int g=0; g<OG; ++g){
    float vB[OC], vD[OC];
    #pragma unroll
    for (int i=0;i<OC;++i){
      int cc = g*OC + i; int kk0 = cc*CH2;
      int ke = kk0+CH2; if (ke>cnt) ke=cnt; ke-=1; if (ke<0) ke=0;
      float pb = PP[((long)b*NN+ke)*FF+f];
      float pm = PM[((long)b*NN+ke)*FF+f];
      bool on = (kk0 < cnt);
      vB[i] = on? pb : 0.f; vD[i] = on? pm : 0.f;
    }
    #pragma unroll
    for (int i=0;i<OC;++i){
      int cc = g*OC + i;
      OFB[base + (long)cc*FF] = rb;
      OFD[base + (long)cc*FF] = rd;
      rb += vB[i]; rd += vD[i];
    }
  }
  OFB[base + (long)NCH2*FF] = rb;
  OFD[base + (long)NCH2*FF] = rd;
}

// ---- layer-1 aggout FUSED with layer-2 projection: writes H2/SI2/SJ2 ----
__global__ __launch_bounds__(128) void k_aggout_mm(
    const float* __restrict__ PP, const float* __restrict__ PM,
    const float* __restrict__ OFB, const float* __restrict__ OFD,
    const float* __restrict__ ROWP,
    const int* __restrict__ cntArr,
    const float* __restrict__ W, const float* __restrict__ aS, const float* __restrict__ aD,
    float* __restrict__ Hout, float* __restrict__ SIo, float* __restrict__ SJo)
{
  int b = blockIdx.y;
  int cnt = cntArr[b];
  int r0 = blockIdx.x*TI;
  if (r0 >= cnt) return;
  int f = threadIdx.x;
  __shared__ float4 srow[TI];
  __shared__ float xs2[TI][FF];
  if (f < TI){
    int r = r0+f; if (r > cnt-1) r = cnt-1;
    srow[f] = reinterpret_cast<const float4*>(ROWP)[(long)b*NN + r];
  }
  __syncthreads();
  const float* ofb = OFB + (long)b*(NCH2+1)*FF;
  const float* ofd = OFD + (long)b*(NCH2+1)*FF;
  float TB = ofb[(long)NCH2*FF + f];
  int rmax = cnt - r0; if (rmax > TI) rmax = TI;
  float pb[TI], pd[TI], ob[TI], od[TI];
  #pragma unroll
  for (int u=0;u<TI;++u){
    int k = __float_as_int(srow[u].w);
    int kc = k-1; if (kc < 0) kc = 0;
    int c = kc/CH2;
    pb[u] = PP[((long)b*NN+kc)*FF+f];
    pd[u] = PM[((long)b*NN+kc)*FF+f];
    ob[u] = ofb[(long)c*FF+f];
    od[u] = ofd[(long)c*FF+f];
  }
  #pragma unroll
  for (int u=0;u<TI;++u){
    float4 rp = srow[u];
    int k = __float_as_int(rp.w);
    bool hasP = (k > 0);
    float PB = hasP ? (pb[u]+ob[u]) : 0.f;
    float PD = hasP ? (pd[u]+od[u]) : 0.f;
    float num = rp.x*(TB-PB) + rp.y*PD;
    float v = 0.f;
    if (u < rmax){
      float o2 = num/rp.z;
      v = (o2>0.f)? o2 : (__expf(o2)-1.f);
    }
    xs2[u][f] = v;
  }
  __syncthreads();
  float acc2[TI];
  #pragma unroll
  for (int u=0;u<TI;++u) acc2[u]=0.f;
  for (int k=0;k<FF;k+=4){
    float w0 = W[(k  )*FF + f];
    float w1 = W[(k+1)*FF + f];
    float w2 = W[(k+2)*FF + f];
    float w3 = W[(k+3)*FF + f];
    #pragma unroll
    for (int u=0;u<TI;++u){
      float4 x = *reinterpret_cast<const float4*>(&xs2[u][k]);
      acc2[u] = fmaf(x.x,w0, fmaf(x.y,w1, fmaf(x.z,w2, fmaf(x.w,w3, acc2[u]))));
    }
  }
  float as = aS[f], ad = aD[f];
  __shared__ float red[2][TI][2];
  #pragma unroll
  for (int u=0;u<TI;++u){
    int rr=r0+u;
    if (rr<cnt) Hout[((long)b*NN+rr)*FF+f] = acc2[u];
    float ps = acc2[u]*as, pd2 = acc2[u]*ad;
    #pragma unroll
    for (int o=32;o;o>>=1){ ps += __shfl_down(ps,o); pd2 += __shfl_down(pd2,o); }
    if ((f&63)==0){ red[0][u][f>>6]=ps; red[1][u][f>>6]=pd2; }
  }
  __syncthreads();
  if (f < TI){
    int rr=r0+f;
    if (rr<cnt){
      SIo[(long)b*NN+rr]=red[0][f][0]+red[0][f][1];
      SJo[(long)b*NN+rr]=red[1][f][0]+red[1][f][1];
    }
  }
}

// ---- FUSED layer-2 aggout + param head + kld + decoder proj + dec partial ----
__global__ __launch_bounds__(256) void k_aggdec(
    const float* __restrict__ PP, const float* __restrict__ PM,
    const float* __restrict__ OFB, const float* __restrict__ OFD,
    const float* __restrict__ ROWP,
    const float* __restrict__ pW, const float* __restrict__ pB,
    const float* __restrict__ decW, const float* __restrict__ dAd,
    const float* __restrict__ sN,
    float* __restrict__ KPART, float* __restrict__ DECP,
    const int* __restrict__ cntArr)
{
  int b = blockIdx.y; int cnt = cntArr[b];
  int bx = blockIdx.x;
  int r0 = bx*8;
  int t = threadIdx.x;
  float* P = DECP + (long)(b*NPB + bx)*(FF+1);
  if (r0>=cnt){
    if (t==0) KPART[b*NPB + bx] = 0.f;
    if (t<=FF) P[t] = 0.f;
    return;
  }
  int f = t & 127, h = t >> 7;
  __shared__ float4 srow[8];
  __shared__ float xs[8][FF];
  if (t < 8){
    int r = r0+t; if (r > cnt-1) r = cnt-1;
    srow[t] = reinterpret_cast<const float4*>(ROWP)[(long)b*NN + r];
  }
  __syncthreads();
  // ---- aggout phase: 4 rows per half ----
  {
    const float* ofb = OFB + (long)b*(NCH2+1)*FF;
    const float* ofd = OFD + (long)b*(NCH2+1)*FF;
    float TB = ofb[(long)NCH2*FF + f];
    int rmax = cnt - r0; if (rmax > 8) rmax = 8;
    float pb[4], pd[4], ob[4], od[4];
    #pragma unroll
    for (int u=0;u<4;++u){
      int rq = h*4+u;
      int k = __float_as_int(srow[rq].w);
      int kc = k-1; if (kc < 0) kc = 0;
      int c = kc/CH2;
      pb[u] = PP[((long)b*NN+kc)*FF+f];
      pd[u] = PM[((long)b*NN+kc)*FF+f];
      ob[u] = ofb[(long)c*FF+f];
      od[u] = ofd[(long)c*FF+f];
    }
    #pragma unroll
    for (int u=0;u<4;++u){
      int rq = h*4+u;
      float4 rp = srow[rq];
      int k = __float_as_int(rp.w);
      bool hasP = (k > 0);
      float PB = hasP ? (pb[u]+ob[u]) : 0.f;
      float PD = hasP ? (pd[u]+od[u]) : 0.f;
      float num = rp.x*(TB-PB) + rp.y*PD;
      float v = 0.f;
      if (rq < rmax){
        float o2 = num/rp.z;
        v = (o2>0.f)? o2 : (__expf(o2)-1.f);
      }
      xs[rq][f] = v;
    }
  }
  __syncthreads();
  // ---- pardec body (round-8 scalar form) ----
  float acc[8]={0.f,0.f,0.f,0.f,0.f,0.f,0.f,0.f};
  for (int k=0;k<FF;++k){
    float w = pW[k*2*FF + t];
    #pragma unroll
    for (int r=0;r<8;++r) acc[r]+=xs[r][k]*w;
  }
  float bb = pB[t];
  float kacc=0.f;
  #pragma unroll
  for (int r=0;r<8;++r){
    int rr=r0+r;
    if (rr>=cnt) continue;
    float v = acc[r]+bb;
    if (t<FF) kacc += v*v;
    else kacc += __expf(v)-v-1.f;
  }
  #pragma unroll
  for (int o=32;o;o>>=1) kacc += __shfl_down(kacc,o);
  __shared__ float rw[4];
  if ((t&63)==0) rw[t>>6]=kacc;
  __syncthreads();
  if (t==0) KPART[b*NPB + bx] = rw[0]+rw[1]+rw[2]+rw[3];
  __shared__ float ms[8][FF];
  if (t < FF){
    #pragma unroll
    for (int r=0;r<8;++r){
      int rr=r0+r;
      ms[r][t] = (rr<cnt) ? acc[r]+bb : 0.f;
    }
  }
  __syncthreads();
  float a2[4]={0.f,0.f,0.f,0.f};
  for (int k=0;k<FF;++k){
    float w = decW[k*FF + f];
    #pragma unroll
    for (int u=0;u<4;++u) a2[u] += ms[h*4+u][k]*w;
  }
  float ad = dAd[f];
  __shared__ float redD[8][2];
  #pragma unroll
  for (int u=0;u<4;++u){
    int rq = h*4+u;
    float pd = a2[u]*ad;
    #pragma unroll
    for (int o=32;o;o>>=1) pd += __shfl_down(pd,o);
    if ((t&63)==0) redD[rq][(t>>6)&1]=pd;
  }
  __syncthreads();
  // decoder partial: w_r = exp(leaky(siN + sj_r)), masked beyond cnt
  float siN = sN[0];
  float accV = 0.f;
  #pragma unroll
  for (int u=0;u<4;++u){
    int rq = h*4+u; int rr = r0+rq;
    float sj = redD[rq][0]+redD[rq][1];
    float x = siN + sj;
    float e = (x>=0.f)? x : SLOPE*x;
    float w = (rr<cnt)? __expf(e) : 0.f;
    accV += w * a2[u];
  }
  __shared__ float pv[2][FF];
  pv[h][f] = accV;
  __syncthreads();
  if (t < FF) P[t] = pv[0][t] + pv[1][t];
  if (t == 0){
    float den = 0.f;
    #pragma unroll
    for (int r=0;r<8;++r){
      int rr = r0+r;
      if (rr>=cnt) continue;
      float sj = redD[r][0]+redD[r][1];
      float x = siN + sj;
      float e = (x>=0.f)? x : SLOPE*x;
      den += __expf(e);
    }
    P[FF] = den;
  }
}

// ---- head: blocks 0..15 = combine partials + MLP; block 16 = kld ----
__global__ __launch_bounds__(128) void k_head(const float* __restrict__ DECP,
    const float* __restrict__ hN, const float* __restrict__ sN,
    const float* __restrict__ KPART, const int* __restrict__ cntArr,
    const float* __restrict__ W1, const float* __restrict__ b1,
    const float* __restrict__ W2, const float* __restrict__ b2,
    float* __restrict__ out)
{
  int b = blockIdx.x;
  int f = threadIdx.x;
  __shared__ float rw[2];
  if (b < BB){
    float siN=sN[0], sjN=sN[1];
    float xN=siN+sjN; float eN=(xN>=0.f)?xN:SLOPE*xN; float wN=__expf(eN);
    float num=0.f, den=0.f;
    for (int c=0;c<NPB;++c){
      const float* P = DECP + (long)(b*NPB+c)*(FF+1);
      num += P[f]; den += P[FF];
    }
    num += wN*hN[f]; den += wN;
    float v = num/den;
    __shared__ float feats[FF];
    feats[f] = (v>0.f)? v : 0.f;
    __syncthreads();
    float acc=0.f;
    for (int k=0;k<FF;k+=4){
      float w0=W1[(k  )*FF+f], w1=W1[(k+1)*FF+f], w2=W1[(k+2)*FF+f], w3=W1[(k+3)*FF+f];
      float4 x = *reinterpret_cast<const float4*>(&feats[k]);
      acc = fmaf(x.x,w0, fmaf(x.y,w1, fmaf(x.z,w2, fmaf(x.w,w3, acc))));
    }
    acc += b1[f];
    acc = (acc>0.f)? acc : 0.f;
    float p = acc*W2[f];
    #pragma unroll
    for (int o=32;o;o>>=1) p += __shfl_down(p,o);
    if ((f&63)==0) rw[f>>6]=p;
    __syncthreads();
    if (f==0) out[b] = rw[0]+rw[1]+b2[0];
  } else {
    float s=0.f;
    for (int bb=0;bb<BB;++bb){
      float part=0.f;
      for (int c=f;c<NPB;c+=128) part += KPART[bb*NPB + c];
      #pragma unroll
      for (int o=32;o;o>>=1) part += __shfl_down(part,o);
      if ((f&63)==0) rw[f>>6]=part;
      __syncthreads();
      float tot = rw[0]+rw[1];
      int c=cntArr[bb]; float cf = (c>0)? (float)c : 1.f;
      s += 0.5f*tot/cf;
      __syncthreads();
    }
    if (f==0) out[16]=s;
  }
}

extern "C" void kernel_launch(void* const* d_in, const int* in_sizes, int n_in,
                              void* d_out, int out_size, void* d_ws, size_t ws_size,
                              hipStream_t stream)
{
  const int*   data  = (const int*)d_in[0];
  const float* embed = (const float*)d_in[1];
  const float* encW  = (const float*)d_in[2];
  const float* encAs = (const float*)d_in[3];
  const float* encAd = (const float*)d_in[4];
  const float* pW    = (const float*)d_in[5];
  const float* pB    = (const float*)d_in[6];
  const float* decW  = (const float*)d_in[7];
  const float* decAs = (const float*)d_in[8];
  const float* decAd = (const float*)d_in[9];
  const float* oW1   = (const float*)d_in[10];
  const float* oB1   = (const float*)d_in[11];
  const float* oW2   = (const float*)d_in[12];
  const float* oB2   = (const float*)d_in[13];
  float* out = (float*)d_out;

  float* w = (float*)d_ws;
  long o = 0;
  float* H1   = w+o; o += (long)NN*FF;
  float* H2   = w+o; o += (long)BB*NN*FF;   // layer-2 proj
  float* PP   = w+o; o += (long)BB*NN*FF;
  float* PM   = w+o; o += (long)BB*NN*FF;
  float* SI1  = w+o; o += NN;
  float* SJ1  = w+o; o += NN;
  float* SI2  = w+o; o += (long)BB*NN;
  float* SJ2  = w+o; o += (long)BB*NN;     // enc layer-2 sj
  float* KPART= w+o; o += (long)BB*NPB;
  float* hN   = w+o; o += FF;
  float* sN   = w+o; o += 2;
  float* DECP = w+o; o += (long)BB*NPB*(FF+1);
  float* keyG = w+o; o += (long)BB*NN;
  float* OFB  = w+o; o += (long)BB*(NCH2+1)*FF;
  float* OFD  = w+o; o += (long)BB*(NCH2+1)*FF;
  o = (o+3) & ~3L;                          // 16B-align ROWP
  float* ROWP = w+o; o += (long)BB*NN*4;
  int* act = (int*)(w+o); o += (long)BB*NN;
  int* pjG = (int*)(w+o); o += (long)BB*NN;
  int* cnt = (int*)(w+o); o += BB;
  int* ctr = (int*)(w+o); o += BB;
  (void)in_sizes; (void)n_in; (void)out_size; (void)ws_size;

  // layer 1 projection (sample-shared)
  k_rowmm<<<NN/8,128,0,stream>>>(embed, encW, encAs, encAd, H1, SI1, SJ1);
  // compaction + sort + scans + row params (block 16: h_N/s_N); resets ctr
  k_sortpre<<<BB+1,1024,0,stream>>>(data, embed, decW, decAs, decAd,
      SJ1, 0L, SI1, 0L, act, cnt, hN, sN, keyG, pjG, ROWP, ctr);
  // chunk prefixes + inline offs scan (last-block pattern)
  k_chunk<<<dim3(NCH2,BB),128,0,stream>>>(keyG, pjG, cnt, H1, 0L, PP, PM,
      OFB, OFD, ctr);
  // layer-1 attention + layer-2 projection fused
  k_aggout_mm<<<dim3(NN/TI,BB),128,0,stream>>>(PP, PM, OFB, OFD, ROWP,
      cnt, encW + FF*FF, encAs + FF, encAd + FF, H2, SI2, SJ2);
  // layer 2 attention (sortpre resets ctr again)
  k_sortpre<<<BB,1024,0,stream>>>(nullptr, embed, decW, decAs, decAd,
      SJ2, (long)NN, SI2, (long)NN, act, cnt, hN, sN, keyG, pjG, ROWP, ctr);
  k_chunk<<<dim3(NCH2,BB),128,0,stream>>>(keyG, pjG, cnt, H2, (long)NN*FF, PP, PM,
      OFB, OFD, ctr);
  // layer-2 aggout + param head + kld + decoder proj + decoder partial, fused
  k_aggdec<<<dim3(NPB,BB),256,0,stream>>>(PP, PM, OFB, OFD, ROWP,
      pW, pB, decW, decAd, sN, KPART, DECP, cnt);
  // combine partials + MLP head + kld sum
  k_head<<<BB+1,128,0,stream>>>(DECP, hN, sN, KPART, cnt, oW1, oB1, oW2, oB2, out);
}

// Round 13
// 226.396 us; speedup vs baseline: 1.9341x; 1.9341x over previous
//
#include <hip/hip_runtime.h>

#define BB 16
#define NN 1536
#define FF 128
#define SLOPE 0.2f
#define NS 2048
#define CH2 16
#define NCH2 96         // NN/CH2
#define TI 8
#define NPB (NN/8)      // 192 aggdec blocks per sample (also DECP partials)
#define OG 4            // k_offs scan groups
#define OC (NCH2/OG)    // 24 chunks per group

// ---- fused: compaction (layer1) + hybrid bitonic sort + scans + row params ----
__global__ __launch_bounds__(1024) void k_sortpre(
    const int* __restrict__ data,            // non-null => layer 1
    const float* __restrict__ embed, const float* __restrict__ decW,
    const float* __restrict__ aS, const float* __restrict__ aD,
    const float* __restrict__ SJb, long sStride,
    const float* __restrict__ SIr, long siStride,
    int* __restrict__ actG, int* __restrict__ cntG,
    float* __restrict__ hN, float* __restrict__ sN,
    float* __restrict__ keyG, int* __restrict__ pjG,
    float* __restrict__ ROWP)
{
  int b = blockIdx.x, t = threadIdx.x;
  if (b == BB){
    __shared__ float rs[2][2];
    if (t < FF){
      float acc = 0.f;
      for (int k=0;k<FF;++k) acc += embed[(long)NN*FF + k] * decW[k*FF + t];
      hN[t] = acc;
      float ps = acc * aS[t];
      float pd = acc * aD[t];
      #pragma unroll
      for (int o=32;o;o>>=1){ ps += __shfl_down(ps,o); pd += __shfl_down(pd,o); }
      if ((t&63)==0){ rs[0][t>>6]=ps; rs[1][t>>6]=pd; }
    }
    __syncthreads();
    if (t==0){ sN[0]=rs[0][0]+rs[0][1]; sN[1]=rs[1][0]+rs[1][1]; }
    return;
  }

  __shared__ float key[NS]; __shared__ int pj[NS];
  __shared__ float sb[NS]; __shared__ float sd[NS];
  __shared__ int cntS;
  int cnt;
  if (data != nullptr){
    __shared__ int s[256];
    const int PER = NN/256;                  // 6
    int local[NN/256]; int nl = 0;
    if (t < 256){
      int base = t*PER;
      #pragma unroll
      for (int u=0; u<PER; ++u){
        if (data[b*NN + base + u] != 0) local[nl++] = base+u;
      }
      s[t]=nl;
    }
    __syncthreads();
    if (t==0){ int run=0; for (int i=0;i<256;i++){ int v=s[i]; s[i]=run; run+=v; }
               cntG[b]=run; cntS=run; }
    __syncthreads();
    if (t < 256){
      int o = s[t];
      for (int u=0; u<nl; ++u) actG[b*NN + o + u] = local[u];
    }
    __syncthreads();
    cnt = cntS;
  } else {
    cnt = cntG[b];
  }

  const float* SJ = SJb + (long)b*sStride;
  const int* act = (data != nullptr) ? actG + b*NN : nullptr;
  int NSort = 32; while (NSort < cnt) NSort <<= 1;    // <= 2048

  for (int e=t; e<NSort; e+=1024){
    if (e<cnt){ int io = act ? act[e] : e; key[e]=SJ[io]; pj[e]=io; }
    else { key[e]=__builtin_inff(); pj[e]=0; }
  }
  __syncthreads();

  // Phase A: k = 2..min(64,NSort) entirely in registers (intra-wave), 0 barriers
  {
    float v0 = (t<NSort)? key[t] : __builtin_inff();
    int   q0 = (t<NSort)? pj[t] : 0;
    float v1 = __builtin_inff(); int q1 = 0;
    bool two = (NSort > 1024);
    if (two){ v1=key[t+1024]; q1=pj[t+1024]; }
    int kmax = (NSort < 64)? NSort : 64;
    for (int k=2; k<=kmax; k<<=1){
      for (int j=k>>1; j>0; j>>=1){
        {
          float ov=__shfl_xor(v0,j); int oq=__shfl_xor(q0,j);
          bool keepmin = (((t & k)==0) == ((t & j)==0));
          bool take = keepmin ? (ov < v0) : (ov > v0);
          if (take){ v0=ov; q0=oq; }
        }
        if (two){
          int e = t+1024;
          float ov=__shfl_xor(v1,j); int oq=__shfl_xor(q1,j);
          bool keepmin = (((e & k)==0) == ((e & j)==0));
          bool take = keepmin ? (ov < v1) : (ov > v1);
          if (take){ v1=ov; q1=oq; }
        }
      }
    }
    if (t < NSort){ key[t]=v0; pj[t]=q0; }
    if (two){ key[t+1024]=v1; pj[t+1024]=q1; }
  }
  __syncthreads();

  // Phase B: k = 128..NSort (LDS for j>=64, shuffles for j<=32)
  for (int k=128; k<=NSort; k<<=1){
    for (int j=k>>1; j>=64; j>>=1){
      for (int e=t; e<NSort; e+=1024){
        int l = e ^ j;
        if (l > e){
          bool asc = ((e & k) == 0);
          float a0=key[e], a1=key[l];
          if (asc ? (a0>a1) : (a0<a1)){
            key[e]=a1; key[l]=a0; int p=pj[e]; pj[e]=pj[l]; pj[l]=p;
          }
        }
      }
      __syncthreads();
    }
    {
      float v0=0.f, v1=0.f; int q0=0, q1=0;
      if (t < NSort){ v0=key[t]; q0=pj[t]; }
      if (NSort > 1024){ v1=key[t+1024]; q1=pj[t+1024]; }
      for (int j=32; j>0; j>>=1){
        {
          float ov=__shfl_xor(v0,j); int oq=__shfl_xor(q0,j);
          bool keepmin = (((t & k)==0) == ((t & j)==0));
          bool take = keepmin ? (ov < v0) : (ov > v0);
          if (take){ v0=ov; q0=oq; }
        }
        if (NSort > 1024){
          int e = t+1024;
          float ov=__shfl_xor(v1,j); int oq=__shfl_xor(q1,j);
          bool keepmin = (((e & k)==0) == ((e & j)==0));
          bool take = keepmin ? (ov < v1) : (ov > v1);
          if (take){ v1=ov; q1=oq; }
        }
      }
      if (t < NSort){ key[t]=v0; pj[t]=q0; }
      if (NSort > 1024){ key[t+1024]=v1; pj[t+1024]=q1; }
    }
    __syncthreads();
  }

  // sb/sd + prefix scan: pair per thread + wave scan + one LDS round
  {
    int e0 = 2*t, e1 = 2*t+1;
    float b0=0.f,b1=0.f,d0=0.f,d1=0.f;
    if (e0 < cnt){ float kk=key[e0]; b0=__expf(kk); d0=__expf(SLOPE*kk); }
    if (e1 < cnt){ float kk=key[e1]; b1=__expf(kk); d1=__expf(SLOPE*kk); }
    float sB=b0+b1, sD=d0+d1;
    int lane = t & 63, wid = t >> 6;
    float iB=sB, iD=sD;
    #pragma unroll
    for (int o=1;o<64;o<<=1){
      float uB=__shfl_up(iB,o), uD=__shfl_up(iD,o);
      if (lane>=o){ iB+=uB; iD+=uD; }
    }
    __shared__ float wsB[16], wsD[16];
    if (lane==63){ wsB[wid]=iB; wsD[wid]=iD; }
    __syncthreads();
    float offB=0.f, offD=0.f;
    for (int w=0; w<wid; ++w){ offB+=wsB[w]; offD+=wsD[w]; }
    float exB = offB + iB - sB;      // exclusive prefix at e0
    float exD = offD + iD - sD;
    if (e0 < NSort){ sb[e0]=exB+b0;    sd[e0]=exD+d0; }
    if (e1 < NSort){ sb[e1]=exB+b0+b1; sd[e1]=exD+d0+d1; }
  }
  __syncthreads();

  // per-row params: boundary search + ai/ci/den, plus keyG/pjG export
  {
    float TBs = sb[(cnt>0)? cnt-1 : 0];
    const float* SIrb = SIr + (data ? 0L : (long)b*siStride);
    for (int r=t; r<cnt; r+=1024){
      float si = data ? SIrb[act[r]] : SIrb[r];
      float th = -si;
      int lo=0, hi=cnt;
      while (lo<hi){ int mid=(lo+hi)>>1; if (key[mid]<=th) lo=mid+1; else hi=mid; }
      float ai=__expf(si), ci=__expf(SLOPE*si);
      float SBv = (lo>0)? sb[lo-1] : 0.f;
      float SDv = (lo>0)? sd[lo-1] : 0.f;
      float4 rp;
      rp.x=ai; rp.y=ci; rp.z = ai*(TBs-SBv)+ci*SDv; rp.w=__int_as_float(lo);
      reinterpret_cast<float4*>(ROWP)[(long)b*NN+r] = rp;
      keyG[(long)b*NN+r]=key[r]; pjG[(long)b*NN+r]=pj[r];
    }
  }
}

// ---- row-matmul (layer 1 only): H = X @ W, SI = H@aSrc, SJ = H@aDst ----
__global__ __launch_bounds__(128) void k_rowmm(const float* __restrict__ Xv,
    const float* __restrict__ W, const float* __restrict__ aS, const float* __restrict__ aD,
    float* __restrict__ H, float* __restrict__ SI, float* __restrict__ SJ)
{
  int r0 = blockIdx.x*8;
  int f = threadIdx.x;
  __shared__ float xs[8][FF];
  #pragma unroll
  for (int r=0;r<8;++r) xs[r][f] = Xv[(long)(r0+r)*FF + f];
  __syncthreads();
  float acc[8]={0.f,0.f,0.f,0.f,0.f,0.f,0.f,0.f};
  for (int k=0;k<FF;k+=4){
    float w0 = W[(k  )*FF + f];
    float w1 = W[(k+1)*FF + f];
    float w2 = W[(k+2)*FF + f];
    float w3 = W[(k+3)*FF + f];
    #pragma unroll
    for (int r=0;r<8;++r){
      float4 x = *reinterpret_cast<const float4*>(&xs[r][k]);
      acc[r] = fmaf(x.x,w0, fmaf(x.y,w1, fmaf(x.z,w2, fmaf(x.w,w3, acc[r]))));
    }
  }
  float as = aS[f], ad = aD[f];
  __shared__ float red[2][8][2];
  #pragma unroll
  for (int r=0;r<8;++r){
    H[(long)(r0+r)*FF + f] = acc[r];
    float ps = acc[r]*as, pd = acc[r]*ad;
    #pragma unroll
    for (int o=32;o;o>>=1){ ps += __shfl_down(ps,o); pd += __shfl_down(pd,o); }
    if ((f&63)==0){ red[0][r][f>>6]=ps; red[1][r][f>>6]=pd; }
  }
  __syncthreads();
  if (f<8){
    SI[r0+f]=red[0][f][0]+red[0][f][1]; SJ[r0+f]=red[1][f][0]+red[1][f][1];
  }
}

// ---- agg stage 2: within-chunk vector prefixes, 8-deep prefetch pipeline ----
__global__ __launch_bounds__(128) void k_chunk(
    const float* __restrict__ keyG, const int* __restrict__ pjG,
    const int* __restrict__ cntArr,
    const float* __restrict__ Hb, long hStride,
    float* __restrict__ PP, float* __restrict__ PM)
{
  int b = blockIdx.y, c = blockIdx.x, f = threadIdx.x;
  int cnt = cntArr[b];
  int k0 = c*CH2;
  if (k0 >= cnt) return;
  int k1 = k0+CH2; if (k1 > cnt) k1 = cnt;
  int kn = k1-k0;
  const float* H = Hb + (long)b*hStride + f;
  __shared__ int pjs[CH2]; __shared__ float wbs[CH2], wds[CH2];
  if (f < CH2 && f < kn){
    float kk = keyG[(long)b*NN + k0 + f];
    pjs[f] = pjG[(long)b*NN + k0 + f];
    wbs[f] = __expf(kk);
    wds[f] = __expf(SLOPE*kk);
  }
  __syncthreads();
  float accB=0.f, accD=0.f;
  float hbuf[8];
  #pragma unroll
  for (int i=0;i<8;i++) hbuf[i] = (i<kn) ? H[(long)pjs[i]*FF] : 0.f;
  long obase = ((long)b*NN + k0)*FF + f;
  int k=0;
  for (; k+8<=kn; k+=8){
    #pragma unroll
    for (int u=0;u<8;u++){
      float hv = hbuf[u];
      int kp = k+u+8;
      hbuf[u] = (kp<kn) ? H[(long)pjs[kp]*FF] : 0.f;
      accB = fmaf(wbs[k+u], hv, accB);
      accD = fmaf(wds[k+u], hv, accD);
      PP[obase + (long)(k+u)*FF] = accB;
      PM[obase + (long)(k+u)*FF] = accD;
    }
  }
  for (; k<kn; ++k){
    float hv = H[(long)pjs[k]*FF];
    accB = fmaf(wbs[k], hv, accB);
    accD = fmaf(wds[k], hv, accD);
    PP[obase + (long)k*FF] = accB;
    PM[obase + (long)k*FF] = accD;
  }
}

// ---- chunk-offset exclusive scan: 4 groups, register-batched loads ----
__global__ __launch_bounds__(512) void k_offs(
    const float* __restrict__ PP, const float* __restrict__ PM,
    const int* __restrict__ cntArr,
    float* __restrict__ OFB, float* __restrict__ OFD)
{
  int b = blockIdx.x; int t = threadIdx.x;
  int f = t & 127, g = t >> 7;           // g in 0..OG-1
  int cnt = cntArr[b];
  float vB[OC], vD[OC];
  #pragma unroll
  for (int i=0;i<OC;++i){
    int c = g*OC + i; int k0 = c*CH2;
    int ke = k0+CH2; if (ke>cnt) ke=cnt; ke-=1; if (ke<0) ke=0;
    float pb = PP[((long)b*NN+ke)*FF+f];
    float pm = PM[((long)b*NN+ke)*FF+f];
    bool on = (k0 < cnt);
    vB[i] = on? pb : 0.f; vD[i] = on? pm : 0.f;
  }
  float rb=0.f, rd=0.f;
  #pragma unroll
  for (int i=0;i<OC;++i){
    float tb=vB[i], td=vD[i];
    vB[i]=rb; vD[i]=rd;
    rb+=tb; rd+=td;
  }
  __shared__ float totB[OG][128], totD[OG][128];
  totB[g][f]=rb; totD[g][f]=rd;
  __syncthreads();
  float ob=0.f, od=0.f;
  #pragma unroll
  for (int q=0;q<OG;++q){ if (q<g){ ob+=totB[q][f]; od+=totD[q][f]; } }
  long base = (long)b*(NCH2+1)*FF + f;
  #pragma unroll
  for (int i=0;i<OC;++i){
    OFB[base + (long)(g*OC+i)*FF] = ob + vB[i];
    OFD[base + (long)(g*OC+i)*FF] = od + vD[i];
  }
  if (g == OG-1){
    OFB[base + (long)NCH2*FF] = ob + rb;
    OFD[base + (long)NCH2*FF] = od + rd;
  }
}

// ---- layer-1 aggout FUSED with layer-2 projection: writes H2/SI2/SJ2 ----
__global__ __launch_bounds__(128) void k_aggout_mm(
    const float* __restrict__ PP, const float* __restrict__ PM,
    const float* __restrict__ OFB, const float* __restrict__ OFD,
    const float* __restrict__ ROWP,
    const int* __restrict__ cntArr,
    const float* __restrict__ W, const float* __restrict__ aS, const float* __restrict__ aD,
    float* __restrict__ Hout, float* __restrict__ SIo, float* __restrict__ SJo)
{
  int b = blockIdx.y;
  int cnt = cntArr[b];
  int r0 = blockIdx.x*TI;
  if (r0 >= cnt) return;
  int f = threadIdx.x;
  __shared__ float4 srow[TI];
  __shared__ float xs2[TI][FF];
  if (f < TI){
    int r = r0+f; if (r > cnt-1) r = cnt-1;
    srow[f] = reinterpret_cast<const float4*>(ROWP)[(long)b*NN + r];
  }
  __syncthreads();
  const float* ofb = OFB + (long)b*(NCH2+1)*FF;
  const float* ofd = OFD + (long)b*(NCH2+1)*FF;
  float TB = ofb[(long)NCH2*FF + f];
  int rmax = cnt - r0; if (rmax > TI) rmax = TI;
  float pb[TI], pd[TI], ob[TI], od[TI];
  #pragma unroll
  for (int u=0;u<TI;++u){
    int k = __float_as_int(srow[u].w);
    int kc = k-1; if (kc < 0) kc = 0;
    int c = kc/CH2;
    pb[u] = PP[((long)b*NN+kc)*FF+f];
    pd[u] = PM[((long)b*NN+kc)*FF+f];
    ob[u] = ofb[(long)c*FF+f];
    od[u] = ofd[(long)c*FF+f];
  }
  #pragma unroll
  for (int u=0;u<TI;++u){
    float4 rp = srow[u];
    int k = __float_as_int(rp.w);
    bool hasP = (k > 0);
    float PB = hasP ? (pb[u]+ob[u]) : 0.f;
    float PD = hasP ? (pd[u]+od[u]) : 0.f;
    float num = rp.x*(TB-PB) + rp.y*PD;
    float v = 0.f;
    if (u < rmax){
      float o2 = num/rp.z;
      v = (o2>0.f)? o2 : (__expf(o2)-1.f);
    }
    xs2[u][f] = v;
  }
  __syncthreads();
  float acc2[TI];
  #pragma unroll
  for (int u=0;u<TI;++u) acc2[u]=0.f;
  for (int k=0;k<FF;k+=4){
    float w0 = W[(k  )*FF + f];
    float w1 = W[(k+1)*FF + f];
    float w2 = W[(k+2)*FF + f];
    float w3 = W[(k+3)*FF + f];
    #pragma unroll
    for (int u=0;u<TI;++u){
      float4 x = *reinterpret_cast<const float4*>(&xs2[u][k]);
      acc2[u] = fmaf(x.x,w0, fmaf(x.y,w1, fmaf(x.z,w2, fmaf(x.w,w3, acc2[u]))));
    }
  }
  float as = aS[f], ad = aD[f];
  __shared__ float red[2][TI][2];
  #pragma unroll
  for (int u=0;u<TI;++u){
    int rr=r0+u;
    if (rr<cnt) Hout[((long)b*NN+rr)*FF+f] = acc2[u];
    float ps = acc2[u]*as, pd2 = acc2[u]*ad;
    #pragma unroll
    for (int o=32;o;o>>=1){ ps += __shfl_down(ps,o); pd2 += __shfl_down(pd2,o); }
    if ((f&63)==0){ red[0][u][f>>6]=ps; red[1][u][f>>6]=pd2; }
  }
  __syncthreads();
  if (f < TI){
    int rr=r0+f;
    if (rr<cnt){
      SIo[(long)b*NN+rr]=red[0][f][0]+red[0][f][1];
      SJo[(long)b*NN+rr]=red[1][f][0]+red[1][f][1];
    }
  }
}

// ---- FUSED layer-2 aggout + param head + kld + decoder proj + dec partial ----
__global__ __launch_bounds__(256) void k_aggdec(
    const float* __restrict__ PP, const float* __restrict__ PM,
    const float* __restrict__ OFB, const float* __restrict__ OFD,
    const float* __restrict__ ROWP,
    const float* __restrict__ pW, const float* __restrict__ pB,
    const float* __restrict__ decW, const float* __restrict__ dAd,
    const float* __restrict__ sN,
    float* __restrict__ KPART, float* __restrict__ DECP,
    const int* __restrict__ cntArr)
{
  int b = blockIdx.y; int cnt = cntArr[b];
  int bx = blockIdx.x;
  int r0 = bx*8;
  int t = threadIdx.x;
  float* P = DECP + (long)(b*NPB + bx)*(FF+1);
  if (r0>=cnt){
    if (t==0) KPART[b*NPB + bx] = 0.f;
    if (t<=FF) P[t] = 0.f;
    return;
  }
  int f = t & 127, h = t >> 7;
  __shared__ float4 srow[8];
  __shared__ float xs[8][FF];
  if (t < 8){
    int r = r0+t; if (r > cnt-1) r = cnt-1;
    srow[t] = reinterpret_cast<const float4*>(ROWP)[(long)b*NN + r];
  }
  __syncthreads();
  // ---- aggout phase: 4 rows per half ----
  {
    const float* ofb = OFB + (long)b*(NCH2+1)*FF;
    const float* ofd = OFD + (long)b*(NCH2+1)*FF;
    float TB = ofb[(long)NCH2*FF + f];
    int rmax = cnt - r0; if (rmax > 8) rmax = 8;
    float pb[4], pd[4], ob[4], od[4];
    #pragma unroll
    for (int u=0;u<4;++u){
      int rq = h*4+u;
      int k = __float_as_int(srow[rq].w);
      int kc = k-1; if (kc < 0) kc = 0;
      int c = kc/CH2;
      pb[u] = PP[((long)b*NN+kc)*FF+f];
      pd[u] = PM[((long)b*NN+kc)*FF+f];
      ob[u] = ofb[(long)c*FF+f];
      od[u] = ofd[(long)c*FF+f];
    }
    #pragma unroll
    for (int u=0;u<4;++u){
      int rq = h*4+u;
      float4 rp = srow[rq];
      int k = __float_as_int(rp.w);
      bool hasP = (k > 0);
      float PB = hasP ? (pb[u]+ob[u]) : 0.f;
      float PD = hasP ? (pd[u]+od[u]) : 0.f;
      float num = rp.x*(TB-PB) + rp.y*PD;
      float v = 0.f;
      if (rq < rmax){
        float o2 = num/rp.z;
        v = (o2>0.f)? o2 : (__expf(o2)-1.f);
      }
      xs[rq][f] = v;
    }
  }
  __syncthreads();
  // ---- pardec body (round-8 scalar form) ----
  float acc[8]={0.f,0.f,0.f,0.f,0.f,0.f,0.f,0.f};
  for (int k=0;k<FF;++k){
    float w = pW[k*2*FF + t];
    #pragma unroll
    for (int r=0;r<8;++r) acc[r]+=xs[r][k]*w;
  }
  float bb = pB[t];
  float kacc=0.f;
  #pragma unroll
  for (int r=0;r<8;++r){
    int rr=r0+r;
    if (rr>=cnt) continue;
    float v = acc[r]+bb;
    if (t<FF) kacc += v*v;
    else kacc += __expf(v)-v-1.f;
  }
  #pragma unroll
  for (int o=32;o;o>>=1) kacc += __shfl_down(kacc,o);
  __shared__ float rw[4];
  if ((t&63)==0) rw[t>>6]=kacc;
  __syncthreads();
  if (t==0) KPART[b*NPB + bx] = rw[0]+rw[1]+rw[2]+rw[3];
  __shared__ float ms[8][FF];
  if (t < FF){
    #pragma unroll
    for (int r=0;r<8;++r){
      int rr=r0+r;
      ms[r][t] = (rr<cnt) ? acc[r]+bb : 0.f;
    }
  }
  __syncthreads();
  float a2[4]={0.f,0.f,0.f,0.f};
  for (int k=0;k<FF;++k){
    float w = decW[k*FF + f];
    #pragma unroll
    for (int u=0;u<4;++u) a2[u] += ms[h*4+u][k]*w;
  }
  float ad = dAd[f];
  __shared__ float redD[8][2];
  #pragma unroll
  for (int u=0;u<4;++u){
    int rq = h*4+u;
    float pd = a2[u]*ad;
    #pragma unroll
    for (int o=32;o;o>>=1) pd += __shfl_down(pd,o);
    if ((t&63)==0) redD[rq][(t>>6)&1]=pd;
  }
  __syncthreads();
  // decoder partial: w_r = exp(leaky(siN + sj_r)), masked beyond cnt
  float siN = sN[0];
  float accV = 0.f;
  #pragma unroll
  for (int u=0;u<4;++u){
    int rq = h*4+u; int rr = r0+rq;
    float sj = redD[rq][0]+redD[rq][1];
    float x = siN + sj;
    float e = (x>=0.f)? x : SLOPE*x;
    float w = (rr<cnt)? __expf(e) : 0.f;
    accV += w * a2[u];
  }
  __shared__ float pv[2][FF];
  pv[h][f] = accV;
  __syncthreads();
  if (t < FF) P[t] = pv[0][t] + pv[1][t];
  if (t == 0){
    float den = 0.f;
    #pragma unroll
    for (int r=0;r<8;++r){
      int rr = r0+r;
      if (rr>=cnt) continue;
      float sj = redD[r][0]+redD[r][1];
      float x = siN + sj;
      float e = (x>=0.f)? x : SLOPE*x;
      den += __expf(e);
    }
    P[FF] = den;
  }
}

// ---- head: blocks 0..15 = combine partials + MLP; block 16 = kld ----
__global__ __launch_bounds__(128) void k_head(const float* __restrict__ DECP,
    const float* __restrict__ hN, const float* __restrict__ sN,
    const float* __restrict__ KPART, const int* __restrict__ cntArr,
    const float* __restrict__ W1, const float* __restrict__ b1,
    const float* __restrict__ W2, const float* __restrict__ b2,
    float* __restrict__ out)
{
  int b = blockIdx.x;
  int f = threadIdx.x;
  __shared__ float rw[2];
  if (b < BB){
    float siN=sN[0], sjN=sN[1];
    float xN=siN+sjN; float eN=(xN>=0.f)?xN:SLOPE*xN; float wN=__expf(eN);
    float num=0.f, den=0.f;
    for (int c=0;c<NPB;++c){
      const float* P = DECP + (long)(b*NPB+c)*(FF+1);
      num += P[f]; den += P[FF];
    }
    num += wN*hN[f]; den += wN;
    float v = num/den;
    __shared__ float feats[FF];
    feats[f] = (v>0.f)? v : 0.f;
    __syncthreads();
    float acc=0.f;
    for (int k=0;k<FF;k+=4){
      float w0=W1[(k  )*FF+f], w1=W1[(k+1)*FF+f], w2=W1[(k+2)*FF+f], w3=W1[(k+3)*FF+f];
      float4 x = *reinterpret_cast<const float4*>(&feats[k]);
      acc = fmaf(x.x,w0, fmaf(x.y,w1, fmaf(x.z,w2, fmaf(x.w,w3, acc))));
    }
    acc += b1[f];
    acc = (acc>0.f)? acc : 0.f;
    float p = acc*W2[f];
    #pragma unroll
    for (int o=32;o;o>>=1) p += __shfl_down(p,o);
    if ((f&63)==0) rw[f>>6]=p;
    __syncthreads();
    if (f==0) out[b] = rw[0]+rw[1]+b2[0];
  } else {
    float s=0.f;
    for (int bb=0;bb<BB;++bb){
      float part=0.f;
      for (int c=f;c<NPB;c+=128) part += KPART[bb*NPB + c];
      #pragma unroll
      for (int o=32;o;o>>=1) part += __shfl_down(part,o);
      if ((f&63)==0) rw[f>>6]=part;
      __syncthreads();
      float tot = rw[0]+rw[1];
      int c=cntArr[bb]; float cf = (c>0)? (float)c : 1.f;
      s += 0.5f*tot/cf;
      __syncthreads();
    }
    if (f==0) out[16]=s;
  }
}

extern "C" void kernel_launch(void* const* d_in, const int* in_sizes, int n_in,
                              void* d_out, int out_size, void* d_ws, size_t ws_size,
                              hipStream_t stream)
{
  const int*   data  = (const int*)d_in[0];
  const float* embed = (const float*)d_in[1];
  const float* encW  = (const float*)d_in[2];
  const float* encAs = (const float*)d_in[3];
  const float* encAd = (const float*)d_in[4];
  const float* pW    = (const float*)d_in[5];
  const float* pB    = (const float*)d_in[6];
  const float* decW  = (const float*)d_in[7];
  const float* decAs = (const float*)d_in[8];
  const float* decAd = (const float*)d_in[9];
  const float* oW1   = (const float*)d_in[10];
  const float* oB1   = (const float*)d_in[11];
  const float* oW2   = (const float*)d_in[12];
  const float* oB2   = (const float*)d_in[13];
  float* out = (float*)d_out;

  float* w = (float*)d_ws;
  long o = 0;
  float* H1   = w+o; o += (long)NN*FF;
  float* H2   = w+o; o += (long)BB*NN*FF;   // layer-2 proj
  float* PP   = w+o; o += (long)BB*NN*FF;
  float* PM   = w+o; o += (long)BB*NN*FF;
  float* SI1  = w+o; o += NN;
  float* SJ1  = w+o; o += NN;
  float* SI2  = w+o; o += (long)BB*NN;
  float* SJ2  = w+o; o += (long)BB*NN;     // enc layer-2 sj
  float* KPART= w+o; o += (long)BB*NPB;
  float* hN   = w+o; o += FF;
  float* sN   = w+o; o += 2;
  float* DECP = w+o; o += (long)BB*NPB*(FF+1);
  float* keyG = w+o; o += (long)BB*NN;
  float* OFB  = w+o; o += (long)BB*(NCH2+1)*FF;
  float* OFD  = w+o; o += (long)BB*(NCH2+1)*FF;
  o = (o+3) & ~3L;                          // 16B-align ROWP
  float* ROWP = w+o; o += (long)BB*NN*4;
  int* act = (int*)(w+o); o += (long)BB*NN;
  int* pjG = (int*)(w+o); o += (long)BB*NN;
  int* cnt = (int*)(w+o); o += BB;
  (void)in_sizes; (void)n_in; (void)out_size; (void)ws_size;

  // layer 1 projection (sample-shared)
  k_rowmm<<<NN/8,128,0,stream>>>(embed, encW, encAs, encAd, H1, SI1, SJ1);
  // compaction + sort + scans + row params (block 16: h_N/s_N)
  k_sortpre<<<BB+1,1024,0,stream>>>(data, embed, decW, decAs, decAd,
      SJ1, 0L, SI1, 0L, act, cnt, hN, sN, keyG, pjG, ROWP);
  k_chunk<<<dim3(NCH2,BB),128,0,stream>>>(keyG, pjG, cnt, H1, 0L, PP, PM);
  k_offs<<<BB,512,0,stream>>>(PP, PM, cnt, OFB, OFD);
  // layer-1 attention + layer-2 projection fused
  k_aggout_mm<<<dim3(NN/TI,BB),128,0,stream>>>(PP, PM, OFB, OFD, ROWP,
      cnt, encW + FF*FF, encAs + FF, encAd + FF, H2, SI2, SJ2);
  // layer 2 attention
  k_sortpre<<<BB,1024,0,stream>>>(nullptr, embed, decW, decAs, decAd,
      SJ2, (long)NN, SI2, (long)NN, act, cnt, hN, sN, keyG, pjG, ROWP);
  k_chunk<<<dim3(NCH2,BB),128,0,stream>>>(keyG, pjG, cnt, H2, (long)NN*FF, PP, PM);
  k_offs<<<BB,512,0,stream>>>(PP, PM, cnt, OFB, OFD);
  // layer-2 aggout + param head + kld + decoder proj + decoder partial, fused
  k_aggdec<<<dim3(NPB,BB),256,0,stream>>>(PP, PM, OFB, OFD, ROWP,
      pW, pB, decW, decAd, sN, KPART, DECP, cnt);
  // combine partials + MLP head + kld sum
  k_head<<<BB+1,128,0,stream>>>(DECP, hN, sN, KPART, cnt, oW1, oB1, oW2, oB2, out);
}